// Round 13
// baseline (38.336 us; speedup 1.0000x reference)
//
#include <hip/hip_runtime.h>
#include <hip/hip_fp16.h>

#define N_SAMP 8192
#define C_CLS  1000
#define A_DIM  2048
#define KDIM   4096   // 2*A_DIM (term1 | term3 folded), in fp8 bytes
#define CP     1024   // padded C
#define ZSPLIT 8

typedef _Float16 half8 __attribute__((ext_vector_type(8)));
typedef _Float16 half4 __attribute__((ext_vector_type(4)));
typedef float    f32x4 __attribute__((ext_vector_type(4)));
typedef unsigned int u32x2 __attribute__((ext_vector_type(2)));

// Scaled fp8 e4m3 operands (values kept in e4m3 normal range; factor 256
// folded out of h in row_nll):
//   A' = [cv | -32*fc*cv],  B' = [256*fc^2 | 16*fc]
__global__ __launch_bounds__(256) void prep_kernel(const float* __restrict__ fc,
                                                   const float* __restrict__ cv,
                                                   unsigned char* __restrict__ Ab,
                                                   unsigned char* __restrict__ Bb) {
    int i4 = blockIdx.x * 256 + threadIdx.x;   // over CP*A_DIM/4
    int c  = i4 >> 9;                          // A_DIM/4 = 512
    int k4 = i4 & 511;
    f32x4 f = {0.f, 0.f, 0.f, 0.f}, v = {0.f, 0.f, 0.f, 0.f};
    if (c < C_CLS) {
        size_t off = (size_t)c * (A_DIM / 4) + k4;
        f = ((const f32x4*)fc)[off];
        v = ((const f32x4*)cv)[off];
    }
    int alo = 0, ahi = 0, blo = 0, bhi = 0;
    alo = __builtin_amdgcn_cvt_pk_fp8_f32(v[0], v[1], alo, 0);
    alo = __builtin_amdgcn_cvt_pk_fp8_f32(v[2], v[3], alo, 1);
    ahi = __builtin_amdgcn_cvt_pk_fp8_f32(-32.f * f[0] * v[0], -32.f * f[1] * v[1], ahi, 0);
    ahi = __builtin_amdgcn_cvt_pk_fp8_f32(-32.f * f[2] * v[2], -32.f * f[3] * v[3], ahi, 1);
    blo = __builtin_amdgcn_cvt_pk_fp8_f32(256.f * f[0] * f[0], 256.f * f[1] * f[1], blo, 0);
    blo = __builtin_amdgcn_cvt_pk_fp8_f32(256.f * f[2] * f[2], 256.f * f[3] * f[3], blo, 1);
    bhi = __builtin_amdgcn_cvt_pk_fp8_f32(16.f * f[0], 16.f * f[1], bhi, 0);
    bhi = __builtin_amdgcn_cvt_pk_fp8_f32(16.f * f[2], 16.f * f[3], bhi, 1);
    size_t ro = (size_t)c * KDIM + k4 * 4;     // byte offsets
    *(int*)(Ab + ro)         = alo;
    *(int*)(Ab + ro + A_DIM) = ahi;
    *(int*)(Bb + ro)         = blo;
    *(int*)(Bb + ro + A_DIM) = bhi;
}

// Spart[z] = A'[:,zKS:(z+1)KS] * B'[:,...]^T, fp8 e4m3 operands, fp8 partials.
// R13: 128x64 tile -> grid (8,16,8) = 1024 blocks = 4 blocks/CU (m145/m102
// proven occupancy regime; R11 showed buying occupancy with K-split costs
// traffic — output-split costs none).  BK=64 fp8, global_load_lds(16B)
// staging (A: 2 slots/thread, B: 1), double-buffered LDS, 4 waves x 64x32,
// granule XOR-swizzle g^((row>>1)&3) on global source + ds_read (rule #21).
// blockIdx.x = z -> linear%8 = XCD id: each K-slice (1MB fp8) L2-resident.
template<int Z>
__global__ __launch_bounds__(256) void gemm_kernel(const unsigned char* __restrict__ A,
                                                   const unsigned char* __restrict__ B,
                                                   unsigned char* __restrict__ Spart) {
    constexpr int KS = KDIM / Z;      // 512 k-bytes per slice
    constexpr int NT = KS / 64;       // 8 tile-steps
    __shared__ unsigned char As[2][128][64];
    __shared__ unsigned char Bs[2][64][64];

    const int z  = blockIdx.x;
    const int tj = blockIdx.y;        // 0..15 (64-col tiles)
    const int tc = blockIdx.z;        // 0..7  (128-row tiles)
    const int tid = threadIdx.x;
    const int lane = tid & 63;
    const int w  = tid >> 6;
    const int wr = w >> 1, wc = w & 1;
    const int k0 = z * KS;

    const size_t arow0 = (size_t)tc * 128;
    const size_t brow0 = (size_t)tj * 64;

#define STAGE(p, kcur)                                                                  \
    {                                                                                   \
        _Pragma("unroll")                                                               \
        for (int issue = 0; issue < 2; ++issue) {                                       \
            int t16 = issue * 256 + tid;                                                \
            int row = t16 >> 2, gp = t16 & 3;                                           \
            int gs  = gp ^ ((row >> 1) & 3);                                            \
            const unsigned char* ga = A + (arow0 + row) * KDIM + (kcur) + gs * 16;      \
            char* la = (char*)&As[p][0][0] + t16 * 16;                                  \
            __builtin_amdgcn_global_load_lds(                                           \
                (const __attribute__((address_space(1))) void*)ga,                      \
                (__attribute__((address_space(3))) void*)la, 16, 0, 0);                 \
        }                                                                               \
        {                                                                               \
            int row = tid >> 2, gp = tid & 3;                                           \
            int gs  = gp ^ ((row >> 1) & 3);                                            \
            const unsigned char* gb = B + (brow0 + row) * KDIM + (kcur) + gs * 16;      \
            char* lb = (char*)&Bs[p][0][0] + tid * 16;                                  \
            __builtin_amdgcn_global_load_lds(                                           \
                (const __attribute__((address_space(1))) void*)gb,                      \
                (__attribute__((address_space(3))) void*)lb, 16, 0, 0);                 \
        }                                                                               \
    }

    f32x4 acc[4][2] = {};
    const int r16 = lane & 15;
    const int g   = lane >> 4;        // k-group: lane reads 8 fp8 at k = kh*32 + g*8

    STAGE(0, k0);
    __syncthreads();
    for (int t = 0; t < NT; ++t) {
        int cur = t & 1;
        if (t + 1 < NT) STAGE(cur ^ 1, k0 + (t + 1) * 64);
        #pragma unroll
        for (int kh = 0; kh < 2; kh++) {
            // logical 16B granule within the 64B row, then XOR-swizzle
            const int gidx = kh * 2 + (g >> 1);
            const int sub  = (g & 1) * 8;
            long af[4], bf[2];
            #pragma unroll
            for (int m = 0; m < 4; m++) {
                int row = wr * 64 + m * 16 + r16;
                af[m] = *(const long*)&As[cur][row][((gidx ^ ((row >> 1) & 3)) << 4) + sub];
            }
            #pragma unroll
            for (int n = 0; n < 2; n++) {
                int row = wc * 32 + n * 16 + r16;
                bf[n] = *(const long*)&Bs[cur][row][((gidx ^ ((row >> 1) & 3)) << 4) + sub];
            }
            #pragma unroll
            for (int m = 0; m < 4; m++)
                #pragma unroll
                for (int n = 0; n < 2; n++)
                    acc[m][n] = __builtin_amdgcn_mfma_f32_16x16x32_fp8_fp8(af[m], bf[n], acc[m][n], 0, 0, 0);
        }
        __syncthreads();   // drains glds (compiler waitcnt) + guards buffer reuse
    }
#undef STAGE

    // C/D layout (verified m89, dtype-independent): col = lane&15, row = (lane>>4)*4 + r
    unsigned char* Sp = Spart + (size_t)z * CP * CP;
    int drow = (lane >> 4) * 4;
    int dcol = lane & 15;
    #pragma unroll
    for (int m = 0; m < 4; m++)
        #pragma unroll
        for (int n = 0; n < 2; n++)
            #pragma unroll
            for (int r = 0; r < 4; r++) {
                int pk = __builtin_amdgcn_cvt_pk_fp8_f32(acc[m][n][r], acc[m][n][r], 0, 0);
                Sp[(size_t)(tc * 128 + wr * 64 + m * 16 + drow + r) * CP
                   + tj * 64 + wc * 32 + n * 16 + dcol] = (unsigned char)(pk & 0xff);
            }
}

// S = sum_z Spart[z] (fp8 in, f32 accumulate, f16 out).  Compact 2 MB S then
// serves row_nll's label-random row reads from L2/L3 (round-3 lesson: fusing
// this into row_nll re-fetched ~100 MB from HBM).
template<int Z>
__global__ __launch_bounds__(256) void ksum_kernel(const unsigned char* __restrict__ Spart,
                                                   _Float16* __restrict__ S) {
    size_t idx = (size_t)blockIdx.x * 256 + threadIdx.x;   // over CP*CP/8 groups
    float a[8] = {};
    #pragma unroll
    for (int z = 0; z < Z; z++) {
        u32x2 v = *(const u32x2*)(Spart + (size_t)z * CP * CP + idx * 8);
        a[0] += __builtin_amdgcn_cvt_f32_fp8(v.x, 0);
        a[1] += __builtin_amdgcn_cvt_f32_fp8(v.x, 1);
        a[2] += __builtin_amdgcn_cvt_f32_fp8(v.x, 2);
        a[3] += __builtin_amdgcn_cvt_f32_fp8(v.x, 3);
        a[4] += __builtin_amdgcn_cvt_f32_fp8(v.y, 0);
        a[5] += __builtin_amdgcn_cvt_f32_fp8(v.y, 1);
        a[6] += __builtin_amdgcn_cvt_f32_fp8(v.y, 2);
        a[7] += __builtin_amdgcn_cvt_f32_fp8(v.y, 3);
    }
    half8 o;
    #pragma unroll
    for (int t = 0; t < 8; t++) o[t] = (_Float16)a[t];
    ((half8*)S)[idx] = o;
}

// One wave per sample: nll_i = LSE_j(y_s[i,j] + h*S[y_i,j]) - value at j=y_i.
// term2 (per-row constant) cancels in the LSE difference. h absorbs the 1/256
// fp8 scaling. target loaded directly at j=y by lane 0 (no in-loop tracking).
// Block partials only; NO fences, NO atomics (round-7 lesson).
__global__ __launch_bounds__(256) void row_nll_kernel(const float* __restrict__ y_s,
                                                      const _Float16* __restrict__ S,
                                                      const int* __restrict__ labels,
                                                      const float* __restrict__ ratio,
                                                      const float* __restrict__ weights,
                                                      float* __restrict__ partial) {
    int lane = threadIdx.x & 63;
    int w = threadIdx.x >> 6;
    int i = blockIdx.x * 4 + w;
    int y = labels[i];
    float h = 0.5f * ratio[0] * (1.0f / 256.0f);
    const float*    ys_row = y_s + (size_t)i * C_CLS;
    const _Float16* s_row  = S   + (size_t)y * CP;

    float v[16];
    float m = -INFINITY;
    #pragma unroll
    for (int k = 0; k < 4; k++) {
        int j = lane * 4 + 256 * k;          // multiple of 4; j<1000 => j+3<=999
        if (j < C_CLS) {
            f32x4 ys = *(const f32x4*)(ys_row + j);
            half4 sv = *(const half4*)(s_row + j);
            #pragma unroll
            for (int t = 0; t < 4; t++) {
                float val = ys[t] + h * (float)sv[t];
                v[k * 4 + t] = val;
                m = fmaxf(m, val);
            }
        } else {
            #pragma unroll
            for (int t = 0; t < 4; t++) v[k * 4 + t] = -INFINITY;
        }
    }
    #pragma unroll
    for (int off = 32; off; off >>= 1) m = fmaxf(m, __shfl_xor(m, off));
    float s = 0.f;
    #pragma unroll
    for (int k = 0; k < 16; k++) s += __expf(v[k] - m);  // exp(-inf)=0 for padding
    #pragma unroll
    for (int off = 32; off; off >>= 1) s += __shfl_xor(s, off);

    __shared__ float swn[4], sww[4];
    if (lane == 0) {
        float target = ys_row[y] + h * (float)s_row[y];  // y < 1000 always
        float wgt = weights[y];
        swn[w] = wgt * ((m + logf(s)) - target);
        sww[w] = wgt;
    }
    __syncthreads();
    if (threadIdx.x == 0) {
        partial[2 * blockIdx.x]     = swn[0] + swn[1] + swn[2] + swn[3];
        partial[2 * blockIdx.x + 1] = sww[0] + sww[1] + sww[2] + sww[3];
    }
}

#define NBLK_NLL (N_SAMP / 4)

__global__ __launch_bounds__(256) void finalize_kernel(const float* __restrict__ partial,
                                                       float* __restrict__ out) {
    float a = 0.f, b = 0.f;
    for (int i = threadIdx.x; i < NBLK_NLL; i += 256) {
        a += partial[2 * i];
        b += partial[2 * i + 1];
    }
    #pragma unroll
    for (int off = 32; off; off >>= 1) { a += __shfl_xor(a, off); b += __shfl_xor(b, off); }
    __shared__ float wa[4], wb[4];
    int w = threadIdx.x >> 6;
    if ((threadIdx.x & 63) == 0) { wa[w] = a; wb[w] = b; }
    __syncthreads();
    if (threadIdx.x == 0)
        out[0] = (wa[0] + wa[1] + wa[2] + wa[3]) / (wb[0] + wb[1] + wb[2] + wb[3]);
}

extern "C" void kernel_launch(void* const* d_in, const int* in_sizes, int n_in,
                              void* d_out, int out_size, void* d_ws, size_t ws_size,
                              hipStream_t stream) {
    const float* fc      = (const float*)d_in[0];
    // d_in[1] = features_source (unused by reference)
    const float* y_s     = (const float*)d_in[2];
    const int*   labels  = (const int*)d_in[3];
    const float* ratio   = (const float*)d_in[4];
    const float* weights = (const float*)d_in[5];
    const float* cv      = (const float*)d_in[6];

    char* ws = (char*)d_ws;
    unsigned char* Abuf  = (unsigned char*)ws;                              // [0, 4 MB)
    unsigned char* Bbuf  = (unsigned char*)(ws + (size_t)4 * 1024 * 1024);  // [4, 8 MB)
    unsigned char* Spart = (unsigned char*)(ws + (size_t)8 * 1024 * 1024);  // 8 * 1 MB -> [8, 16 MB)
    _Float16*      S     = (_Float16*)(ws + (size_t)16 * 1024 * 1024);      // 2 MB
    float*         part  = (float*)   (ws + (size_t)18 * 1024 * 1024);      // 16 KB

    prep_kernel<<<(CP * A_DIM / 4) / 256, 256, 0, stream>>>(fc, cv, Abuf, Bbuf);
    gemm_kernel<ZSPLIT><<<dim3(ZSPLIT, 16, 8), 256, 0, stream>>>(Abuf, Bbuf, Spart);
    ksum_kernel<ZSPLIT><<<(CP * CP / 8) / 256, 256, 0, stream>>>(Spart, S);
    row_nll_kernel<<<NBLK_NLL, 256, 0, stream>>>(y_s, S, labels, ratio, weights, part);
    finalize_kernel<<<1, 256, 0, stream>>>(part, (float*)d_out);
}

// Round 14
// 35.903 us; speedup vs baseline: 1.0678x; 1.0678x over previous
//
#include <hip/hip_runtime.h>
#include <hip/hip_fp16.h>

#define N_SAMP 8192
#define C_CLS  1000
#define A_DIM  2048
#define KDIM   4096   // 2*A_DIM (term1 | term3 folded), in fp8 bytes
#define CP     1024   // padded C
#define ZSPLIT 8

typedef _Float16 half8 __attribute__((ext_vector_type(8)));
typedef _Float16 half4 __attribute__((ext_vector_type(4)));
typedef float    f32x4 __attribute__((ext_vector_type(4)));
typedef float    f32x16 __attribute__((ext_vector_type(16)));
typedef int      i32x4 __attribute__((ext_vector_type(4)));
typedef int      i32x8 __attribute__((ext_vector_type(8)));
typedef unsigned int u32x2 __attribute__((ext_vector_type(2)));

// Scaled fp8 e4m3 operands (values kept in e4m3 normal range; factor 256
// folded out of h in row_nll):
//   A' = [cv | -32*fc*cv],  B' = [256*fc^2 | 16*fc]
__global__ __launch_bounds__(256) void prep_kernel(const float* __restrict__ fc,
                                                   const float* __restrict__ cv,
                                                   unsigned char* __restrict__ Ab,
                                                   unsigned char* __restrict__ Bb) {
    int i4 = blockIdx.x * 256 + threadIdx.x;   // over CP*A_DIM/4
    int c  = i4 >> 9;                          // A_DIM/4 = 512
    int k4 = i4 & 511;
    f32x4 f = {0.f, 0.f, 0.f, 0.f}, v = {0.f, 0.f, 0.f, 0.f};
    if (c < C_CLS) {
        size_t off = (size_t)c * (A_DIM / 4) + k4;
        f = ((const f32x4*)fc)[off];
        v = ((const f32x4*)cv)[off];
    }
    int alo = 0, ahi = 0, blo = 0, bhi = 0;
    alo = __builtin_amdgcn_cvt_pk_fp8_f32(v[0], v[1], alo, 0);
    alo = __builtin_amdgcn_cvt_pk_fp8_f32(v[2], v[3], alo, 1);
    ahi = __builtin_amdgcn_cvt_pk_fp8_f32(-32.f * f[0] * v[0], -32.f * f[1] * v[1], ahi, 0);
    ahi = __builtin_amdgcn_cvt_pk_fp8_f32(-32.f * f[2] * v[2], -32.f * f[3] * v[3], ahi, 1);
    blo = __builtin_amdgcn_cvt_pk_fp8_f32(256.f * f[0] * f[0], 256.f * f[1] * f[1], blo, 0);
    blo = __builtin_amdgcn_cvt_pk_fp8_f32(256.f * f[2] * f[2], 256.f * f[3] * f[3], blo, 1);
    bhi = __builtin_amdgcn_cvt_pk_fp8_f32(16.f * f[0], 16.f * f[1], bhi, 0);
    bhi = __builtin_amdgcn_cvt_pk_fp8_f32(16.f * f[2], 16.f * f[3], bhi, 1);
    size_t ro = (size_t)c * KDIM + k4 * 4;     // byte offsets
    *(int*)(Ab + ro)         = alo;
    *(int*)(Ab + ro + A_DIM) = ahi;
    *(int*)(Bb + ro)         = blo;
    *(int*)(Bb + ro + A_DIM) = bhi;
}

// Spart[z] = A'[:,zKS:(z+1)KS] * B'[:,...]^T, fp8 e4m3 operands, fp8 partials.
// R14: MX-scale MFMA 32x32x64 f8f6f4 with UNITY scales (e8m0 127 = 1.0) as a
// plain fp8 GEMM at 2x issue rate (ladder 3-mx, m148): one 64-k step = 4 MFMA
// instead of 32.  Same numerics (fp8 in, f32 accum).  Staging identical to
// R12: 128x128 tile, BK=64, global_load_lds(16B), double-buffered LDS,
// granule XOR-swizzle g^((row>>1)&3) on global source + ds_read (rule #21).
// Fragments: A/B row = lane&31, k-bytes = (lane>>5)*32 + [0..32) -> two
// swizzled ds_read_b128.  C/D 32x32 layout verified m74/m101 (dtype-indep).
// blockIdx.x = z -> linear%8 = XCD id: each K-slice (1MB fp8) L2-resident.
template<int Z>
__global__ __launch_bounds__(256) void gemm_kernel(const unsigned char* __restrict__ A,
                                                   const unsigned char* __restrict__ B,
                                                   unsigned char* __restrict__ Spart) {
    constexpr int KS = KDIM / Z;      // 512 k-bytes per slice
    constexpr int NT = KS / 64;       // 8 tile-steps
    __shared__ unsigned char As[2][128][64];
    __shared__ unsigned char Bs[2][128][64];

    const int z  = blockIdx.x;
    const int tj = blockIdx.y;
    const int tc = blockIdx.z;
    const int tid = threadIdx.x;
    const int lane = tid & 63;
    const int w  = tid >> 6;
    const int wr = w >> 1, wc = w & 1;
    const int k0 = z * KS;

    const size_t arow0 = (size_t)tc * 128;
    const size_t brow0 = (size_t)tj * 128;

#define STAGE(p, kcur)                                                                  \
    {                                                                                   \
        _Pragma("unroll")                                                               \
        for (int issue = 0; issue < 2; ++issue) {                                       \
            int t16 = issue * 256 + tid;                                                \
            int row = t16 >> 2, gp = t16 & 3;                                           \
            int gs  = gp ^ ((row >> 1) & 3);                                            \
            const unsigned char* ga = A + (arow0 + row) * KDIM + (kcur) + gs * 16;      \
            const unsigned char* gb = B + (brow0 + row) * KDIM + (kcur) + gs * 16;      \
            char* la = (char*)&As[p][0][0] + t16 * 16;                                  \
            char* lb = (char*)&Bs[p][0][0] + t16 * 16;                                  \
            __builtin_amdgcn_global_load_lds(                                           \
                (const __attribute__((address_space(1))) void*)ga,                      \
                (__attribute__((address_space(3))) void*)la, 16, 0, 0);                 \
            __builtin_amdgcn_global_load_lds(                                           \
                (const __attribute__((address_space(1))) void*)gb,                      \
                (__attribute__((address_space(3))) void*)lb, 16, 0, 0);                 \
        }                                                                               \
    }

    f32x16 acc[2][2] = {};
    const int r32   = lane & 31;
    const int khalf = lane >> 5;      // k-bytes [khalf*32, khalf*32+32)
    const int g0 = khalf * 2, g1 = khalf * 2 + 1;

    STAGE(0, k0);
    __syncthreads();
    for (int t = 0; t < NT; ++t) {
        int cur = t & 1;
        if (t + 1 < NT) STAGE(cur ^ 1, k0 + (t + 1) * 64);
        i32x8 af[2], bf[2];
        #pragma unroll
        for (int m = 0; m < 2; m++) {
            int row = wr * 64 + m * 32 + r32;
            int sw  = (row >> 1) & 3;
            i32x4 lo = *(const i32x4*)&As[cur][row][(g0 ^ sw) << 4];
            i32x4 hi = *(const i32x4*)&As[cur][row][(g1 ^ sw) << 4];
            af[m] = __builtin_shufflevector(lo, hi, 0, 1, 2, 3, 4, 5, 6, 7);
        }
        #pragma unroll
        for (int n = 0; n < 2; n++) {
            int row = wc * 64 + n * 32 + r32;
            int sw  = (row >> 1) & 3;
            i32x4 lo = *(const i32x4*)&Bs[cur][row][(g0 ^ sw) << 4];
            i32x4 hi = *(const i32x4*)&Bs[cur][row][(g1 ^ sw) << 4];
            bf[n] = __builtin_shufflevector(lo, hi, 0, 1, 2, 3, 4, 5, 6, 7);
        }
        #pragma unroll
        for (int m = 0; m < 2; m++)
            #pragma unroll
            for (int n = 0; n < 2; n++)
                acc[m][n] = __builtin_amdgcn_mfma_scale_f32_32x32x64_f8f6f4(
                    af[m], bf[n], acc[m][n], 0 /*fp8*/, 0 /*fp8*/,
                    0, 127 /*scaleA=1.0*/, 0, 127 /*scaleB=1.0*/);
        __syncthreads();   // drains glds (compiler waitcnt) + guards buffer reuse
    }
#undef STAGE

    // C/D 32x32 layout (verified m74/m101, dtype-independent):
    //   col = lane&31, row = (r&3) + 8*(r>>2) + 4*(lane>>5), r in [0,16)
    unsigned char* Sp = Spart + (size_t)z * CP * CP;
    #pragma unroll
    for (int m = 0; m < 2; m++)
        #pragma unroll
        for (int n = 0; n < 2; n++)
            #pragma unroll
            for (int r = 0; r < 16; r++) {
                int orow = (r & 3) + 8 * (r >> 2) + 4 * khalf;
                int pk = __builtin_amdgcn_cvt_pk_fp8_f32(acc[m][n][r], acc[m][n][r], 0, 0);
                Sp[(size_t)(tc * 128 + wr * 64 + m * 32 + orow) * CP
                   + tj * 128 + wc * 64 + n * 32 + r32] = (unsigned char)(pk & 0xff);
            }
}

// S = sum_z Spart[z] (fp8 in, f32 accumulate, f16 out).  Compact 2 MB S then
// serves row_nll's label-random row reads from L2/L3 (round-3 lesson: fusing
// this into row_nll re-fetched ~100 MB from HBM).
template<int Z>
__global__ __launch_bounds__(256) void ksum_kernel(const unsigned char* __restrict__ Spart,
                                                   _Float16* __restrict__ S) {
    size_t idx = (size_t)blockIdx.x * 256 + threadIdx.x;   // over CP*CP/8 groups
    float a[8] = {};
    #pragma unroll
    for (int z = 0; z < Z; z++) {
        u32x2 v = *(const u32x2*)(Spart + (size_t)z * CP * CP + idx * 8);
        a[0] += __builtin_amdgcn_cvt_f32_fp8(v.x, 0);
        a[1] += __builtin_amdgcn_cvt_f32_fp8(v.x, 1);
        a[2] += __builtin_amdgcn_cvt_f32_fp8(v.x, 2);
        a[3] += __builtin_amdgcn_cvt_f32_fp8(v.x, 3);
        a[4] += __builtin_amdgcn_cvt_f32_fp8(v.y, 0);
        a[5] += __builtin_amdgcn_cvt_f32_fp8(v.y, 1);
        a[6] += __builtin_amdgcn_cvt_f32_fp8(v.y, 2);
        a[7] += __builtin_amdgcn_cvt_f32_fp8(v.y, 3);
    }
    half8 o;
    #pragma unroll
    for (int t = 0; t < 8; t++) o[t] = (_Float16)a[t];
    ((half8*)S)[idx] = o;
}

// One wave per sample: nll_i = LSE_j(y_s[i,j] + h*S[y_i,j]) - value at j=y_i.
// term2 (per-row constant) cancels in the LSE difference. h absorbs the 1/256
// fp8 scaling. target loaded directly at j=y by lane 0 (no in-loop tracking).
// Block partials only; NO fences, NO atomics (round-7 lesson).
__global__ __launch_bounds__(256) void row_nll_kernel(const float* __restrict__ y_s,
                                                      const _Float16* __restrict__ S,
                                                      const int* __restrict__ labels,
                                                      const float* __restrict__ ratio,
                                                      const float* __restrict__ weights,
                                                      float* __restrict__ partial) {
    int lane = threadIdx.x & 63;
    int w = threadIdx.x >> 6;
    int i = blockIdx.x * 4 + w;
    int y = labels[i];
    float h = 0.5f * ratio[0] * (1.0f / 256.0f);
    const float*    ys_row = y_s + (size_t)i * C_CLS;
    const _Float16* s_row  = S   + (size_t)y * CP;

    float v[16];
    float m = -INFINITY;
    #pragma unroll
    for (int k = 0; k < 4; k++) {
        int j = lane * 4 + 256 * k;          // multiple of 4; j<1000 => j+3<=999
        if (j < C_CLS) {
            f32x4 ys = *(const f32x4*)(ys_row + j);
            half4 sv = *(const half4*)(s_row + j);
            #pragma unroll
            for (int t = 0; t < 4; t++) {
                float val = ys[t] + h * (float)sv[t];
                v[k * 4 + t] = val;
                m = fmaxf(m, val);
            }
        } else {
            #pragma unroll
            for (int t = 0; t < 4; t++) v[k * 4 + t] = -INFINITY;
        }
    }
    #pragma unroll
    for (int off = 32; off; off >>= 1) m = fmaxf(m, __shfl_xor(m, off));
    float s = 0.f;
    #pragma unroll
    for (int k = 0; k < 16; k++) s += __expf(v[k] - m);  // exp(-inf)=0 for padding
    #pragma unroll
    for (int off = 32; off; off >>= 1) s += __shfl_xor(s, off);

    __shared__ float swn[4], sww[4];
    if (lane == 0) {
        float target = ys_row[y] + h * (float)s_row[y];  // y < 1000 always
        float wgt = weights[y];
        swn[w] = wgt * ((m + logf(s)) - target);
        sww[w] = wgt;
    }
    __syncthreads();
    if (threadIdx.x == 0) {
        partial[2 * blockIdx.x]     = swn[0] + swn[1] + swn[2] + swn[3];
        partial[2 * blockIdx.x + 1] = sww[0] + sww[1] + sww[2] + sww[3];
    }
}

#define NBLK_NLL (N_SAMP / 4)

__global__ __launch_bounds__(256) void finalize_kernel(const float* __restrict__ partial,
                                                       float* __restrict__ out) {
    float a = 0.f, b = 0.f;
    for (int i = threadIdx.x; i < NBLK_NLL; i += 256) {
        a += partial[2 * i];
        b += partial[2 * i + 1];
    }
    #pragma unroll
    for (int off = 32; off; off >>= 1) { a += __shfl_xor(a, off); b += __shfl_xor(b, off); }
    __shared__ float wa[4], wb[4];
    int w = threadIdx.x >> 6;
    if ((threadIdx.x & 63) == 0) { wa[w] = a; wb[w] = b; }
    __syncthreads();
    if (threadIdx.x == 0)
        out[0] = (wa[0] + wa[1] + wa[2] + wa[3]) / (wb[0] + wb[1] + wb[2] + wb[3]);
}

extern "C" void kernel_launch(void* const* d_in, const int* in_sizes, int n_in,
                              void* d_out, int out_size, void* d_ws, size_t ws_size,
                              hipStream_t stream) {
    const float* fc      = (const float*)d_in[0];
    // d_in[1] = features_source (unused by reference)
    const float* y_s     = (const float*)d_in[2];
    const int*   labels  = (const int*)d_in[3];
    const float* ratio   = (const float*)d_in[4];
    const float* weights = (const float*)d_in[5];
    const float* cv      = (const float*)d_in[6];

    char* ws = (char*)d_ws;
    unsigned char* Abuf  = (unsigned char*)ws;                              // [0, 4 MB)
    unsigned char* Bbuf  = (unsigned char*)(ws + (size_t)4 * 1024 * 1024);  // [4, 8 MB)
    unsigned char* Spart = (unsigned char*)(ws + (size_t)8 * 1024 * 1024);  // 8 * 1 MB -> [8, 16 MB)
    _Float16*      S     = (_Float16*)(ws + (size_t)16 * 1024 * 1024);      // 2 MB
    float*         part  = (float*)   (ws + (size_t)18 * 1024 * 1024);      // 16 KB

    prep_kernel<<<(CP * A_DIM / 4) / 256, 256, 0, stream>>>(fc, cv, Abuf, Bbuf);
    gemm_kernel<ZSPLIT><<<dim3(ZSPLIT, 8, 8), 256, 0, stream>>>(Abuf, Bbuf, Spart);
    ksum_kernel<ZSPLIT><<<(CP * CP / 8) / 256, 256, 0, stream>>>(Spart, S);
    row_nll_kernel<<<NBLK_NLL, 256, 0, stream>>>(y_s, S, labels, ratio, weights, part);
    finalize_kernel<<<1, 256, 0, stream>>>(part, (float*)d_out);
}